// Round 14
// baseline (1308.920 us; speedup 1.0000x reference)
//
#include <hip/hip_runtime.h>

// AssociativeScanGateLoop: h_t = f_t*h_{t-1} + i_t*v_t per (b,d) sequence.
// x: (B=4, T=8192, 3*512) fp32.  out: (4, 8192, 512) fp32.
//
// v7: single-kernel decoupled-lookback chained scan (CUB DeviceScan pattern).
// Evidence: v5/v6 exonerated occupancy, ILP, compute, and raw BW; remaining
// structure = serialized phases + KS kernel + gaps. Lookback removes all 3:
// blocks flow phase1 -> publish agg -> lookback h0 -> publish inclusive ->
// phase3, with no global barrier, so chunk phases overlap across blocks.
// All 2048 blocks co-resident (128 thr, launch_bounds(128,4) => >=8 blk/CU),
// so spin-waits are deadlock-free regardless of dispatch order.

#define B_   4
#define T_   8192
#define DH_  512
#define ROW_ 1536
#define C_   512
#define TC_  16          // T_ / C_

// clang ext-vector: __builtin_nontemporal_store requires this, not HIP float4.
typedef float f32x4 __attribute__((ext_vector_type(4)));

__device__ __forceinline__ float rcp_f(float x) {
    return __builtin_amdgcn_rcpf(x);   // v_rcp_f32 — avoids div expansion
}
__device__ __forceinline__ float sigmoid_f(float x) {
    return rcp_f(1.0f + __expf(-x));
}
__device__ __forceinline__ float tanh_f(float x) {
    // 1 - 2/(e^{2x}+1): saturates to +/-1 even when __expf overflows to inf.
    return 1.0f - 2.0f * rcp_f(__expf(2.0f * x) + 1.0f);
}

// status[b*C_+c]: 0 = invalid, 1 = aggregate published, 2 = inclusive published.
__global__ __launch_bounds__(128, 4)
void k_lookback(const float* __restrict__ x,
                float* __restrict__ out,
                float* __restrict__ agg_a,
                float* __restrict__ agg_kv,
                float* __restrict__ h_incl,
                int* __restrict__ status) {
    const int c = blockIdx.x;            // chunk
    const int b = blockIdx.y;            // batch
    const int d = threadIdx.x << 2;      // channel base (4 per thread)
    const float* xb = x + ((size_t)b * T_ + (size_t)c * TC_) * ROW_;

    // ---- phase 1: per-chunk affine aggregate (A, KV)
    float A[4] = {1.f, 1.f, 1.f, 1.f};
    float K[4] = {0.f, 0.f, 0.f, 0.f};
#pragma unroll 8
    for (int i = 0; i < TC_; ++i) {
        const float* r = xb + (size_t)i * ROW_;
        const f32x4 xi = *(const f32x4*)(r + d);
        const f32x4 gi = *(const f32x4*)(r + DH_ + d);
#pragma unroll
        for (int j = 0; j < 4; ++j) {
            const float s  = sigmoid_f(gi[j]);
            const float f  = 1.0f - s;
            const float iv = tanh_f(xi[j]) * s;
            A[j] *= f;
            K[j] = fmaf(f, K[j], iv);
        }
    }

    const size_t cbase = ((size_t)b * C_ + c) * DH_ + d;
    // Publish aggregate via agent-scope (device-coherent) stores, then flag.
#pragma unroll
    for (int j = 0; j < 4; ++j) {
        __hip_atomic_store(agg_a  + cbase + j, A[j], __ATOMIC_RELAXED, __HIP_MEMORY_SCOPE_AGENT);
        __hip_atomic_store(agg_kv + cbase + j, K[j], __ATOMIC_RELAXED, __HIP_MEMORY_SCOPE_AGENT);
    }
    __syncthreads();                     // all agg stores globally visible
    if (threadIdx.x == 0)
        __hip_atomic_store(status + b * C_ + c, 1, __ATOMIC_RELEASE, __HIP_MEMORY_SCOPE_AGENT);

    // ---- lookback: h0 = state entering this chunk (h_init = 0)
    float h0[4] = {0.f, 0.f, 0.f, 0.f};
    if (c > 0) {
        float Ap[4] = {1.f, 1.f, 1.f, 1.f};
        float Kp[4] = {0.f, 0.f, 0.f, 0.f};
        int cc = c - 1;
        while (cc >= 0) {
            const int* sp = status + b * C_ + cc;
            int st;
            do {
                st = __hip_atomic_load(sp, __ATOMIC_ACQUIRE, __HIP_MEMORY_SCOPE_AGENT);
            } while (st == 0);
            const size_t pb = ((size_t)b * C_ + cc) * DH_ + d;
            if (st == 2) {               // inclusive state available: finish
#pragma unroll
                for (int j = 0; j < 4; ++j) {
                    const float hi = __hip_atomic_load(h_incl + pb + j, __ATOMIC_RELAXED, __HIP_MEMORY_SCOPE_AGENT);
                    h0[j] = fmaf(Ap[j], hi, Kp[j]);
                }
                break;
            } else {                     // aggregate only: fold, keep walking
#pragma unroll
                for (int j = 0; j < 4; ++j) {
                    const float ac = __hip_atomic_load(agg_a  + pb + j, __ATOMIC_RELAXED, __HIP_MEMORY_SCOPE_AGENT);
                    const float kc = __hip_atomic_load(agg_kv + pb + j, __ATOMIC_RELAXED, __HIP_MEMORY_SCOPE_AGENT);
                    Kp[j] = fmaf(Ap[j], kc, Kp[j]);
                    Ap[j] *= ac;
                }
                --cc;
            }
        }
        if (cc < 0) {                    // walked off the front: h_incl(-1)=0
#pragma unroll
            for (int j = 0; j < 4; ++j) h0[j] = Kp[j];
        }
    }

    // Publish inclusive state, then flag 2.
#pragma unroll
    for (int j = 0; j < 4; ++j) {
        const float hi = fmaf(A[j], h0[j], K[j]);
        __hip_atomic_store(h_incl + cbase + j, hi, __ATOMIC_RELAXED, __HIP_MEMORY_SCOPE_AGENT);
    }
    __syncthreads();
    if (threadIdx.x == 0)
        __hip_atomic_store(status + b * C_ + c, 2, __ATOMIC_RELEASE, __HIP_MEMORY_SCOPE_AGENT);

    // ---- phase 3: recompute chunk with carried state, write gated output.
    float h[4];
#pragma unroll
    for (int j = 0; j < 4; ++j) h[j] = h0[j];

    float* ob = out + ((size_t)b * T_ + (size_t)c * TC_) * DH_;
#pragma unroll 8
    for (int i = 0; i < TC_; ++i) {
        const float* r = xb + (size_t)i * ROW_;
        const f32x4 xi = *(const f32x4*)(r + d);          // L2-hot from phase 1
        const f32x4 gi = *(const f32x4*)(r + DH_ + d);    // L2-hot
        const f32x4 go = *(const f32x4*)(r + 2 * DH_ + d);
        f32x4 o;
#pragma unroll
        for (int j = 0; j < 4; ++j) {
            const float s  = sigmoid_f(gi[j]);
            const float f  = 1.0f - s;
            const float iv = tanh_f(xi[j]) * s;
            h[j] = fmaf(f, h[j], iv);
            o[j] = tanh_f(h[j]) * sigmoid_f(go[j]);
        }
        // out is never re-read: nontemporal store leaves cache to x.
        __builtin_nontemporal_store(o, (f32x4*)(ob + (size_t)i * DH_ + d));
    }
}

// Fallback (no usable workspace): sequential per-channel pass. Correct, slow.
__global__ void k_seq(const float* __restrict__ x, float* __restrict__ out) {
    const int b = blockIdx.x;
    const int d4 = threadIdx.x << 2;
    const float* xb = x + (size_t)b * T_ * ROW_;
    float* ob = out + (size_t)b * T_ * DH_;
    float h[4] = {0.f, 0.f, 0.f, 0.f};
    for (int i = 0; i < T_; ++i) {
        const float* r = xb + (size_t)i * ROW_;
        const f32x4 xi = *(const f32x4*)(r + d4);
        const f32x4 gi = *(const f32x4*)(r + DH_ + d4);
        const f32x4 go = *(const f32x4*)(r + 2 * DH_ + d4);
        f32x4 o;
#pragma unroll
        for (int j = 0; j < 4; ++j) {
            const float s  = sigmoid_f(gi[j]);
            const float f  = 1.0f - s;
            const float iv = tanh_f(xi[j]) * s;
            h[j] = fmaf(f, h[j], iv);
            o[j] = tanh_f(h[j]) * sigmoid_f(go[j]);
        }
        *(f32x4*)(ob + (size_t)i * DH_ + d4) = o;
    }
}

extern "C" void kernel_launch(void* const* d_in, const int* in_sizes, int n_in,
                              void* d_out, int out_size, void* d_ws, size_t ws_size,
                              hipStream_t stream) {
    const float* x = (const float*)d_in[0];
    float* out = (float*)d_out;

    const size_t n_agg = (size_t)B_ * C_ * DH_;          // 1M floats = 4 MiB
    const size_t need  = 3 * n_agg * sizeof(float) + (size_t)B_ * C_ * sizeof(int);
    if (ws_size < need) {
        hipLaunchKernelGGL(k_seq, dim3(B_), dim3(DH_ / 4), 0, stream, x, out);
        return;
    }

    float* agg_a  = (float*)d_ws;
    float* agg_kv = agg_a  + n_agg;
    float* h_incl = agg_kv + n_agg;
    int*   status = (int*)(h_incl + n_agg);

    // Zero the status flags (workspace arrives poisoned). 8 KB, capturable.
    hipMemsetAsync(status, 0, (size_t)B_ * C_ * sizeof(int), stream);

    hipLaunchKernelGGL(k_lookback, dim3(C_, B_), dim3(DH_ / 4), 0, stream,
                       x, out, agg_a, agg_kv, h_incl, status);
}